// Round 4
// baseline (132.575 us; speedup 1.0000x reference)
//
#include <hip/hip_runtime.h>
#include <math.h>

// Problem shape (fixed by setup_inputs): B=8192 rows, D=2048 cols, fp32.
static constexpr int Dn = 2048;
static constexpr int Bn = 8192;
static constexpr int NBLK  = 512;        // 256 thr each -> 2048 waves, 8 waves/CU
static constexpr int NWAVE = NBLK * 4;
static constexpr int ROWS  = Bn / NWAVE; // 4 rows per wave

// Native clang vector: __builtin_nontemporal_load requires scalar/ext-vector,
// not HIP_vector_type<float,4>.
typedef float f4 __attribute__((ext_vector_type(4)));

__device__ __forceinline__ float dot4(f4 a, f4 b) {
    return a.x * b.x + a.y * b.y + a.z * b.z + a.w * b.w;
}

// Fused main kernel, wave-per-row, 4 rows/wave, 2-deep row pipeline:
//  - anchor a = embed[0]/max(||.||,1e-12) built in registers per wave (8 KB,
//    L2-hot broadcast; setup amortized over 4 rows)
//  - row j+1's loads issued before row j's butterfly so the 12-shuffle serial
//    reduce overlaps in-flight VMEM within the wave
//  - ee rows loaded non-temporally (read-once stream; keep L2 for anchor/labels)
//  - lane 0 accumulates fp64 partials (j != 0 masked), one SoA triple per wave
__global__ __launch_bounds__(256) void k_main(const float* __restrict__ embed,
                                              const float* __restrict__ ee,
                                              const float* __restrict__ labels,
                                              double* __restrict__ part) {
    const int t    = threadIdx.x;
    const int lane = t & 63;
    const int wv   = ((int)blockIdx.x << 2) | (t >> 6);  // global wave id

    // ---- anchor fragment: lane owns float4 columns {s*64 + lane}, s = 0..7 ----
    const f4* e0 = reinterpret_cast<const f4*>(embed);
    f4 av[8];
    float ss = 0.f;
#pragma unroll
    for (int s = 0; s < 8; ++s) {
        av[s] = e0[(s << 6) + lane];
        ss += dot4(av[s], av[s]);
    }
#pragma unroll
    for (int o = 32; o > 0; o >>= 1) ss += __shfl_xor(ss, o, 64);
    const float inv = 1.0f / fmaxf(sqrtf(ss), 1e-12f);

    float ssa = 0.f;
#pragma unroll
    for (int s = 0; s < 8; ++s) {
        av[s] *= inv;
        ssa += dot4(av[s], av[s]);
    }
#pragma unroll
    for (int o = 32; o > 0; o >>= 1) ssa += __shfl_xor(ssa, o, 64);
    const float na = fmaxf(sqrtf(ssa), 1e-6f);  // = max(||a||, 1e-6), cos eps

    // ---- labels prefetch (lane 0 only uses them) ----
    float lb[ROWS];
    if (lane == 0) {
#pragma unroll
        for (int r = 0; r < ROWS; ++r) lb[r] = labels[wv + r * NWAVE];
    }

    // ---- pipelined row loop: 4 rows per wave ----
    double sE = 0.0, sL = 0.0, sN = 0.0;
    f4 cur[8], nxt[8];
    {
        const f4* row = reinterpret_cast<const f4*>(ee + (size_t)wv * Dn);
#pragma unroll
        for (int s = 0; s < 8; ++s)
            cur[s] = __builtin_nontemporal_load(&row[(s << 6) + lane]);
    }
#pragma unroll
    for (int r = 0; r < ROWS; ++r) {
        const int j = wv + r * NWAVE;
        if (r + 1 < ROWS) {  // prefetch next row before reducing this one
            const f4* rn = reinterpret_cast<const f4*>(ee + (size_t)(j + NWAVE) * Dn);
#pragma unroll
            for (int s = 0; s < 8; ++s)
                nxt[s] = __builtin_nontemporal_load(&rn[(s << 6) + lane]);
        }
        float dt = 0.f, sr = 0.f;
#pragma unroll
        for (int s = 0; s < 8; ++s) {
            dt += dot4(cur[s], av[s]);
            sr += dot4(cur[s], cur[s]);
        }
#pragma unroll
        for (int o = 32; o > 0; o >>= 1) {
            dt += __shfl_xor(dt, o, 64);
            sr += __shfl_xor(sr, o, 64);
        }
        if (lane == 0 && j != 0) {
            const float nb  = fmaxf(sqrtf(sr), 1e-6f);
            const float neg = -10.0f * dt / (na * nb);   // -cos/T, T = 0.1
            sE += (double)expf(neg);
            sL += (double)lb[r];
            sN += (double)lb[r] * (double)neg;
        }
#pragma unroll
        for (int s = 0; s < 8; ++s) cur[s] = nxt[s];
    }
    if (lane == 0) {
        part[wv]             = sE;   // SoA for coalesced finisher reads
        part[NWAVE + wv]     = sL;
        part[2 * NWAVE + wv] = sN;
    }
}

// Finisher: 1 block, fp64 reduce of 2048 wave-partials, then the scalar math:
//   E0 = 1e-12 + SE;  C0 = 1e-12 + l0*SL
//   L0 = -(l0/C0) * (SN - log(E0)*SL);  out = L0/B
__global__ __launch_bounds__(256) void k_final(const double* __restrict__ part,
                                               const float* __restrict__ labels,
                                               float* __restrict__ out) {
    __shared__ double rE[4], rL[4], rN[4];
    const int t = threadIdx.x;
    const int lane = t & 63, wave = t >> 6;

    double sE = 0.0, sL = 0.0, sN = 0.0;
    for (int i = t; i < NWAVE; i += 256) {
        sE += part[i];
        sL += part[NWAVE + i];
        sN += part[2 * NWAVE + i];
    }
#pragma unroll
    for (int o = 32; o > 0; o >>= 1) {
        sE += __shfl_down(sE, o, 64);
        sL += __shfl_down(sL, o, 64);
        sN += __shfl_down(sN, o, 64);
    }
    if (lane == 0) { rE[wave] = sE; rL[wave] = sL; rN[wave] = sN; }
    __syncthreads();
    if (t == 0) {
        const double E0 = 1e-12 + rE[0] + rE[1] + rE[2] + rE[3];
        const double S2 = rL[0] + rL[1] + rL[2] + rL[3];
        const double S3 = rN[0] + rN[1] + rN[2] + rN[3];
        const double l0 = (double)labels[0];
        const double C0 = 1e-12 + l0 * S2;
        const double L0 = -(l0 / C0) * (S3 - log(E0) * S2);
        out[0] = (float)(L0 / (double)Bn);
    }
}

extern "C" void kernel_launch(void* const* d_in, const int* in_sizes, int n_in,
                              void* d_out, int out_size, void* d_ws, size_t ws_size,
                              hipStream_t stream) {
    const float* embed  = (const float*)d_in[0];  // [B, D] — only row 0 used
    const float* ee     = (const float*)d_in[1];  // [B, D]
    const float* labels = (const float*)d_in[2];  // [B]
    float* out = (float*)d_out;

    double* part = (double*)d_ws;  // 3 * NWAVE doubles = 48 KB, fully overwritten

    k_main<<<NBLK, 256, 0, stream>>>(embed, ee, labels, part);
    k_final<<<1, 256, 0, stream>>>(part, labels, out);
}

// Round 5
// 127.993 us; speedup vs baseline: 1.0358x; 1.0358x over previous
//
#include <hip/hip_runtime.h>
#include <math.h>

// Problem shape (fixed by setup_inputs): B=8192 rows, D=2048 cols, fp32.
static constexpr int Dn = 2048;
static constexpr int Bn = 8192;
static constexpr int NBLK  = 1024;       // 256 thr each -> 4096 waves, 4 waves/SIMD
static constexpr int NWAVE = NBLK * 4;   // 2 rows per wave

typedef float f4 __attribute__((ext_vector_type(4)));

__device__ __forceinline__ float dot4(f4 a, f4 b) {
    return a.x * b.x + a.y * b.y + a.z * b.z + a.w * b.w;
}

// Fused main kernel. Per wave:
//  - issue BOTH rows' 8+8 dwordx4 loads first (16 outstanding HBM loads/lane)
//  - while they fly, build the normalized anchor a = embed[0]/max(||.||,1e-12)
//    in registers (8 KB L2-hot broadcast; its ~800-cycle serial chain hides
//    under the row loads)
//  - in-lane dot/norm FMAs, then two independent 6-step __shfl_xor butterflies
//    (dual-issued; no LDS, no barriers)
//  - lane 0 accumulates fp64 partials of sum(exp(neg)), sum(labels),
//    sum(labels*neg) over its rows (j != 0 masked), one SoA triple per wave.
__global__ __launch_bounds__(256) void k_main(const float* __restrict__ embed,
                                              const float* __restrict__ ee,
                                              const float* __restrict__ labels,
                                              double* __restrict__ part) {
    const int t    = threadIdx.x;
    const int lane = t & 63;
    const int wv   = ((int)blockIdx.x << 2) | (t >> 6);  // global wave id
    const int j0   = wv;                                  // row pair
    const int j1   = wv + NWAVE;

    // ---- both rows' loads issued first: 16 dwordx4 in flight per lane ----
    const f4* r0 = reinterpret_cast<const f4*>(ee + (size_t)j0 * Dn);
    const f4* r1 = reinterpret_cast<const f4*>(ee + (size_t)j1 * Dn);
    f4 x0[8], x1[8];
#pragma unroll
    for (int s = 0; s < 8; ++s) x0[s] = r0[(s << 6) + lane];
#pragma unroll
    for (int s = 0; s < 8; ++s) x1[s] = r1[(s << 6) + lane];

    // labels early too (lane 0 only consumes them)
    float lb0 = 0.f, lb1 = 0.f;
    if (lane == 0) { lb0 = labels[j0]; lb1 = labels[j1]; }

    // ---- anchor fragment (overlaps the row loads) ----
    const f4* e0 = reinterpret_cast<const f4*>(embed);
    f4 av[8];
    float ss = 0.f;
#pragma unroll
    for (int s = 0; s < 8; ++s) {
        av[s] = e0[(s << 6) + lane];
        ss += dot4(av[s], av[s]);
    }
#pragma unroll
    for (int o = 32; o > 0; o >>= 1) ss += __shfl_xor(ss, o, 64);
    const float inv = 1.0f / fmaxf(sqrtf(ss), 1e-12f);

    float ssa = 0.f;
#pragma unroll
    for (int s = 0; s < 8; ++s) {
        av[s] *= inv;
        ssa += dot4(av[s], av[s]);
    }
#pragma unroll
    for (int o = 32; o > 0; o >>= 1) ssa += __shfl_xor(ssa, o, 64);
    const float na = fmaxf(sqrtf(ssa), 1e-6f);  // = max(||a||, 1e-6), cos eps

    // ---- in-lane dots for both rows ----
    float dt0 = 0.f, sr0 = 0.f, dt1 = 0.f, sr1 = 0.f;
#pragma unroll
    for (int s = 0; s < 8; ++s) {
        dt0 += dot4(x0[s], av[s]);
        sr0 += dot4(x0[s], x0[s]);
        dt1 += dot4(x1[s], av[s]);
        sr1 += dot4(x1[s], x1[s]);
    }

    // ---- four independent butterfly chains (dual-issue pairs) ----
#pragma unroll
    for (int o = 32; o > 0; o >>= 1) {
        dt0 += __shfl_xor(dt0, o, 64);
        dt1 += __shfl_xor(dt1, o, 64);
        sr0 += __shfl_xor(sr0, o, 64);
        sr1 += __shfl_xor(sr1, o, 64);
    }

    if (lane == 0) {
        double sE = 0.0, sL = 0.0, sN = 0.0;
        if (j0 != 0) {  // mask: exclude j == i == 0 (j0 == 0 only for wave 0)
            const float nb  = fmaxf(sqrtf(sr0), 1e-6f);
            const float neg = -10.0f * dt0 / (na * nb);  // -cos/T, T = 0.1
            sE += (double)expf(neg);
            sL += (double)lb0;
            sN += (double)lb0 * (double)neg;
        }
        {
            const float nb  = fmaxf(sqrtf(sr1), 1e-6f);
            const float neg = -10.0f * dt1 / (na * nb);
            sE += (double)expf(neg);
            sL += (double)lb1;
            sN += (double)lb1 * (double)neg;
        }
        part[wv]             = sE;   // SoA for coalesced finisher reads
        part[NWAVE + wv]     = sL;
        part[2 * NWAVE + wv] = sN;
    }
}

// Finisher: 1 block, fp64 reduce of 4096 wave-partials, then the scalar math:
//   E0 = 1e-12 + SE;  C0 = 1e-12 + l0*SL
//   L0 = -(l0/C0) * (SN - log(E0)*SL);  out = L0/B
__global__ __launch_bounds__(256) void k_final(const double* __restrict__ part,
                                               const float* __restrict__ labels,
                                               float* __restrict__ out) {
    __shared__ double rE[4], rL[4], rN[4];
    const int t = threadIdx.x;
    const int lane = t & 63, wave = t >> 6;

    double sE = 0.0, sL = 0.0, sN = 0.0;
    for (int i = t; i < NWAVE; i += 256) {
        sE += part[i];
        sL += part[NWAVE + i];
        sN += part[2 * NWAVE + i];
    }
#pragma unroll
    for (int o = 32; o > 0; o >>= 1) {
        sE += __shfl_down(sE, o, 64);
        sL += __shfl_down(sL, o, 64);
        sN += __shfl_down(sN, o, 64);
    }
    if (lane == 0) { rE[wave] = sE; rL[wave] = sL; rN[wave] = sN; }
    __syncthreads();
    if (t == 0) {
        const double E0 = 1e-12 + rE[0] + rE[1] + rE[2] + rE[3];
        const double S2 = rL[0] + rL[1] + rL[2] + rL[3];
        const double S3 = rN[0] + rN[1] + rN[2] + rN[3];
        const double l0 = (double)labels[0];
        const double C0 = 1e-12 + l0 * S2;
        const double L0 = -(l0 / C0) * (S3 - log(E0) * S2);
        out[0] = (float)(L0 / (double)Bn);
    }
}

extern "C" void kernel_launch(void* const* d_in, const int* in_sizes, int n_in,
                              void* d_out, int out_size, void* d_ws, size_t ws_size,
                              hipStream_t stream) {
    const float* embed  = (const float*)d_in[0];  // [B, D] — only row 0 used
    const float* ee     = (const float*)d_in[1];  // [B, D]
    const float* labels = (const float*)d_in[2];  // [B]
    float* out = (float*)d_out;

    double* part = (double*)d_ws;  // 3 * NWAVE doubles = 96 KB, fully overwritten

    k_main<<<NBLK, 256, 0, stream>>>(embed, ee, labels, part);
    k_final<<<1, 256, 0, stream>>>(part, labels, out);
}